// Round 1
// baseline (496.516 us; speedup 1.0000x reference)
//
#include <hip/hip_runtime.h>

// ---------------------------------------------------------------------------
// MultiheadAttention  B=4 S=2048 D=1024 H=16 DK=64
// Pipeline: f32->f16 convert -> 3 proj GEMMs -> flash attention -> out GEMM
// All matmul in f16 MFMA (16x16x32), f32 accumulate.
// ---------------------------------------------------------------------------

typedef _Float16 f16;
typedef _Float16 f16x8 __attribute__((ext_vector_type(8)));
typedef _Float16 f16x4 __attribute__((ext_vector_type(4)));
typedef float f32x4 __attribute__((ext_vector_type(4)));

#define MFMA16(a, b, c) __builtin_amdgcn_mfma_f32_16x16x32_f16((a), (b), (c), 0, 0, 0)

__device__ __forceinline__ f32x4 vmax4(f32x4 a, f32x4 b) {
  f32x4 r;
  r[0] = fmaxf(a[0], b[0]);
  r[1] = fmaxf(a[1], b[1]);
  r[2] = fmaxf(a[2], b[2]);
  r[3] = fmaxf(a[3], b[3]);
  return r;
}

// ---------------- conversion kernels ----------------
// q,k,v: 3 arrays of 8388608 f32 -> f16.  8192 blocks per array.
__global__ void cvt_qkv_kernel(const float* __restrict__ q, const float* __restrict__ k,
                               const float* __restrict__ v, f16* __restrict__ qo,
                               f16* __restrict__ ko, f16* __restrict__ vo, int* __restrict__ flags) {
  if (blockIdx.x == 0 && threadIdx.x < 2) flags[threadIdx.x] = 0;  // zero mask flags (stream-ordered before mask_flags_kernel)
  const int a = blockIdx.x >> 13;
  const long idx = (long)((blockIdx.x & 8191) * 256 + threadIdx.x) * 4;
  const float* src = (a == 0) ? q : (a == 1) ? k : v;
  f16* dst = (a == 0) ? qo : (a == 1) ? ko : vo;
  const float4 f = *reinterpret_cast<const float4*>(src + idx);
  f16x4 o;
  o[0] = (f16)f.x; o[1] = (f16)f.y; o[2] = (f16)f.z; o[3] = (f16)f.w;
  *reinterpret_cast<f16x4*>(dst + idx) = o;
}

// 4 weight matrices of 1048576 f32 -> f16. 1024 blocks per array.
__global__ void cvt_w_kernel(const float* __restrict__ w0, const float* __restrict__ w1,
                             const float* __restrict__ w2, const float* __restrict__ w3,
                             f16* __restrict__ o0, f16* __restrict__ o1,
                             f16* __restrict__ o2, f16* __restrict__ o3) {
  const int a = blockIdx.x >> 10;
  const long idx = (long)((blockIdx.x & 1023) * 256 + threadIdx.x) * 4;
  const float* src = (a == 0) ? w0 : (a == 1) ? w1 : (a == 2) ? w2 : w3;
  f16* dst = (a == 0) ? o0 : (a == 1) ? o1 : (a == 2) ? o2 : o3;
  const float4 f = *reinterpret_cast<const float4*>(src + idx);
  f16x4 o;
  o[0] = (f16)f.x; o[1] = (f16)f.y; o[2] = (f16)f.z; o[3] = (f16)f.w;
  *reinterpret_cast<f16x4*>(dst + idx) = o;
}

// OR-reduce the two bool masks into flags[0] (attn_mask any) / flags[1] (kpm any).
__global__ void mask_flags_kernel(const unsigned char* __restrict__ am,
                                  const unsigned char* __restrict__ kp, int* __restrict__ flags) {
  const int tid = blockIdx.x * 256 + threadIdx.x;  // 262144 threads == 4MB/16
  const uint4 u = reinterpret_cast<const uint4*>(am)[tid];
  if (u.x | u.y | u.z | u.w) atomicOr(flags, 1);
  if (tid < 512) {
    const uint4 w = reinterpret_cast<const uint4*>(kp)[tid];
    if (w.x | w.y | w.z | w.w) atomicOr(flags + 1, 1);
  }
}

// ---------------- GEMM: C[M,N] = A[M,K] * B[N,K]^T + bias[N] ----------------
// 128x128 tile, 4 waves each 64x64 (4x4 fragments of 16x16x32), BK=64.
// Reg-staged LDS with XOR swizzle (byte ^= (row&7)<<4) to kill ds_read_b128
// bank conflicts (G4: row-major 128B-stride tiles are 16-way conflicted).
__device__ __forceinline__ void stC(float* p, float v) { *p = v; }
__device__ __forceinline__ void stC(f16* p, float v) { *p = (f16)v; }

template <typename OutT>
__global__ __launch_bounds__(256) void gemm_bt(const f16* __restrict__ A, const f16* __restrict__ B,
                                               const float* __restrict__ bias, OutT* __restrict__ C,
                                               int M, int N, int K) {
  __shared__ __align__(16) char As[16384];
  __shared__ __align__(16) char Bs[16384];
  const int tid = threadIdx.x;
  const int w = tid >> 6, lane = tid & 63, t = lane & 15, g = lane >> 4;
  const int nb = N >> 7;
  const int br = blockIdx.x / nb, bc = blockIdx.x - br * nb;
  const int rowBase = br << 7, colBase = bc << 7;
  const int wr = w >> 1, wc = w & 1;

  f32x4 acc[4][4];
#pragma unroll
  for (int m = 0; m < 4; ++m)
#pragma unroll
    for (int n = 0; n < 4; ++n) acc[m][n] = (f32x4){0.f, 0.f, 0.f, 0.f};

  const int nk = K >> 6;
  for (int ks = 0; ks < nk; ++ks) {
    const int k0 = ks << 6;
    // stage A and B tiles: 1024 16B-chunks each; thread covers 4 chunks per tile.
    f16x8 va[4], vb[4];
#pragma unroll
    for (int c = 0; c < 4; ++c) {
      const int li = (c * 4 + w) * 64 + lane;  // chunk index 0..1023
      const int row = li >> 3;                 // 8 chunks per 128B row
      const int colb = (li & 7) << 4;          // byte col in row
      va[c] = *reinterpret_cast<const f16x8*>(A + (size_t)(rowBase + row) * K + k0 + (colb >> 1));
      vb[c] = *reinterpret_cast<const f16x8*>(B + (size_t)(colBase + row) * K + k0 + (colb >> 1));
    }
    __syncthreads();  // previous iteration's readers done
#pragma unroll
    for (int c = 0; c < 4; ++c) {
      const int li = (c * 4 + w) * 64 + lane;
      const int row = li >> 3;
      const int colb = (li & 7) << 4;
      const int sw = colb ^ ((row & 7) << 4);
      *reinterpret_cast<f16x8*>(As + row * 128 + sw) = va[c];
      *reinterpret_cast<f16x8*>(Bs + row * 128 + sw) = vb[c];
    }
    __syncthreads();  // tile staged
#pragma unroll
    for (int kk = 0; kk < 2; ++kk) {
      f16x8 af[4], bf[4];
#pragma unroll
      for (int m = 0; m < 4; ++m) {
        const int row = (wr << 6) + (m << 4) + t;
        af[m] = *reinterpret_cast<const f16x8*>(As + row * 128 + (((kk << 6) + (g << 4)) ^ ((row & 7) << 4)));
      }
#pragma unroll
      for (int n = 0; n < 4; ++n) {
        const int row = (wc << 6) + (n << 4) + t;
        bf[n] = *reinterpret_cast<const f16x8*>(Bs + row * 128 + (((kk << 6) + (g << 4)) ^ ((row & 7) << 4)));
      }
#pragma unroll
      for (int m = 0; m < 4; ++m)
#pragma unroll
        for (int n = 0; n < 4; ++n) acc[m][n] = MFMA16(af[m], bf[n], acc[m][n]);
    }
  }
  // epilogue: bias add, store. D frag: col = lane&15, row = (lane>>4)*4 + r (m89-verified).
#pragma unroll
  for (int n = 0; n < 4; ++n) {
    const int col = colBase + (wc << 6) + (n << 4) + t;
    const float bv = bias[col];
#pragma unroll
    for (int m = 0; m < 4; ++m) {
      const int row0 = rowBase + (wr << 6) + (m << 4) + (g << 2);
#pragma unroll
      for (int r = 0; r < 4; ++r) stC(C + (size_t)(row0 + r) * N + col, acc[m][n][r] + bv);
    }
  }
}

// ---------------- flash attention ----------------
// Layouts: qh/kh/vh/y are [B*S, H*DK] f16 (row = b*2048+s, col = h*64+dk).
// Block: 256 thr = 4 waves; QBLK=128 (32 q-rows per wave, 2 strips of 16); KVBLK=64.
// K fragments straight from global (L1/L2: all 4 waves share addresses).
// V transposed into swizzled LDS; P transposed through per-wave swizzled LDS.
__global__ __launch_bounds__(256) void attn_kernel(const f16* __restrict__ qh, const f16* __restrict__ kh,
                                                   const f16* __restrict__ vh,
                                                   const unsigned char* __restrict__ am,
                                                   const unsigned char* __restrict__ kp,
                                                   const int* __restrict__ flags, f16* __restrict__ y) {
  __shared__ __align__(16) char VT[8192];    // [64 dk][64 kv] f16, swizzled
  __shared__ __align__(16) char PB[16384];   // per-wave [32 q][64 kv] f16, swizzled
  const int tid = threadIdx.x;
  const int w = tid >> 6, lane = tid & 63, t = lane & 15, g = lane >> 4;
  const int qt = blockIdx.x & 15, bh = blockIdx.x >> 4;
  const int h = bh & 15, b = bh >> 4;
  const int hc = h << 6;
  const size_t rowQ0 = (size_t)b * 2048 + qt * 128 + w * 32;
  const size_t kvRow0 = (size_t)b * 2048;

  f16x8 aq[2][2];
#pragma unroll
  for (int m = 0; m < 2; ++m) {
    const f16* qp = qh + (rowQ0 + m * 16 + t) * 1024 + hc + g * 8;
    aq[m][0] = *reinterpret_cast<const f16x8*>(qp);
    aq[m][1] = *reinterpret_cast<const f16x8*>(qp + 32);
  }
  f32x4 o[2][4];
#pragma unroll
  for (int m = 0; m < 2; ++m)
#pragma unroll
    for (int d = 0; d < 4; ++d) o[m][d] = (f32x4){0.f, 0.f, 0.f, 0.f};
  f32x4 mx[2], ls[2];
#pragma unroll
  for (int m = 0; m < 2; ++m) {
    mx[m] = (f32x4){-3.0e38f, -3.0e38f, -3.0e38f, -3.0e38f};
    ls[m] = (f32x4){0.f, 0.f, 0.f, 0.f};
  }
  const int f0 = flags[0], f1 = flags[1];
  char* PBw = PB + (w << 12);

  for (int tk = 0; tk < 32; ++tk) {
    const int kv0 = tk << 6;
    __syncthreads();  // previous tile's LDS readers done
    {  // stage V^T: thread loads V[kv0+kvr][hc+half*16 .. +32), scatters transposed
      const int kvr = tid & 63, half = tid >> 6;
      const f16* vp = vh + (kvRow0 + kv0 + kvr) * 1024 + hc + (half << 4);
      const f16x8 v0 = *reinterpret_cast<const f16x8*>(vp);
      const f16x8 v1 = *reinterpret_cast<const f16x8*>(vp + 8);
#pragma unroll
      for (int j = 0; j < 8; ++j) {
        const int dk = (half << 4) + j;
        *reinterpret_cast<f16*>(VT + dk * 128 + ((kvr * 2) ^ ((dk & 7) << 4))) = v0[j];
      }
#pragma unroll
      for (int j = 0; j < 8; ++j) {
        const int dk = (half << 4) + 8 + j;
        *reinterpret_cast<f16*>(VT + dk * 128 + ((kvr * 2) ^ ((dk & 7) << 4))) = v1[j];
      }
    }
    // QK^T: scores s[m][kvt], D frag rows = q (g*4+r), cols = kv (t)
    f32x4 s[2][4];
#pragma unroll
    for (int kvt = 0; kvt < 4; ++kvt) {
      const f16* kr = kh + (kvRow0 + kv0 + kvt * 16 + t) * 1024 + hc + g * 8;
      const f16x8 bk0 = *reinterpret_cast<const f16x8*>(kr);
      const f16x8 bk1 = *reinterpret_cast<const f16x8*>(kr + 32);
#pragma unroll
      for (int m = 0; m < 2; ++m) {
        f32x4 z = (f32x4){0.f, 0.f, 0.f, 0.f};
        z = MFMA16(aq[m][0], bk0, z);
        z = MFMA16(aq[m][1], bk1, z);
        s[m][kvt] = z;
      }
    }
#pragma unroll
    for (int m = 0; m < 2; ++m)
#pragma unroll
      for (int kvt = 0; kvt < 4; ++kvt) s[m][kvt] *= 0.125f;  // 1/sqrt(64)
    if (f0 | f1) {  // mask slow path (wave-uniform; inputs here are all-false -> skipped)
      for (int m = 0; m < 2; ++m)
        for (int kvt = 0; kvt < 4; ++kvt) {
          const int kv = kv0 + kvt * 16 + t;
          const bool kbad = f1 && kp[(size_t)b * 2048 + kv];
          for (int r = 0; r < 4; ++r) {
            const int q = qt * 128 + w * 32 + m * 16 + g * 4 + r;
            if (kbad || (f0 && am[(size_t)q * 2048 + kv])) s[m][kvt][r] = -1e9f;
          }
        }
    }
    // online softmax per strip m (rows replicated across the 16 t-lanes of each g-group)
#pragma unroll
    for (int m = 0; m < 2; ++m) {
      f32x4 tm = vmax4(vmax4(s[m][0], s[m][1]), vmax4(s[m][2], s[m][3]));
#pragma unroll
      for (int d = 1; d < 16; d <<= 1) {
        tm[0] = fmaxf(tm[0], __shfl_xor(tm[0], d));
        tm[1] = fmaxf(tm[1], __shfl_xor(tm[1], d));
        tm[2] = fmaxf(tm[2], __shfl_xor(tm[2], d));
        tm[3] = fmaxf(tm[3], __shfl_xor(tm[3], d));
      }
      const f32x4 nm = vmax4(mx[m], tm);
      f32x4 al;
#pragma unroll
      for (int r = 0; r < 4; ++r) al[r] = __expf(mx[m][r] - nm[r]);
      mx[m] = nm;
      f32x4 psum = (f32x4){0.f, 0.f, 0.f, 0.f};
#pragma unroll
      for (int kvt = 0; kvt < 4; ++kvt) {
        f32x4 p;
#pragma unroll
        for (int r = 0; r < 4; ++r) p[r] = __expf(s[m][kvt][r] - nm[r]);
        psum += p;
#pragma unroll
        for (int r = 0; r < 4; ++r) {
          const int prow = (m << 4) + (g << 2) + r;
          *reinterpret_cast<f16*>(PBw + prow * 128 + (((kvt << 5) + t * 2) ^ ((prow & 7) << 4))) = (f16)p[r];
        }
      }
      ls[m] = ls[m] * al + psum;
#pragma unroll
      for (int d = 0; d < 4; ++d) o[m][d] *= al;
    }
    __syncthreads();  // V^T staged + P visible
    // PV: O[m] += P(32x64) * V(64x64)
#pragma unroll
    for (int kk = 0; kk < 2; ++kk) {
      f16x8 pa[2], bvv[4];
#pragma unroll
      for (int m = 0; m < 2; ++m) {
        const int prow = (m << 4) + t;
        pa[m] = *reinterpret_cast<const f16x8*>(PBw + prow * 128 + (((kk << 6) + (g << 4)) ^ ((prow & 7) << 4)));
      }
#pragma unroll
      for (int d = 0; d < 4; ++d) {
        const int dk = (d << 4) + t;
        bvv[d] = *reinterpret_cast<const f16x8*>(VT + dk * 128 + (((kk << 6) + (g << 4)) ^ ((dk & 7) << 4)));
      }
#pragma unroll
      for (int m = 0; m < 2; ++m)
#pragma unroll
        for (int d = 0; d < 4; ++d) o[m][d] = MFMA16(pa[m], bvv[d], o[m][d]);
    }
  }
  // normalize + store y (f16)
#pragma unroll
  for (int m = 0; m < 2; ++m) {
#pragma unroll
    for (int d = 1; d < 16; d <<= 1) {
      ls[m][0] += __shfl_xor(ls[m][0], d);
      ls[m][1] += __shfl_xor(ls[m][1], d);
      ls[m][2] += __shfl_xor(ls[m][2], d);
      ls[m][3] += __shfl_xor(ls[m][3], d);
    }
    f32x4 inv;
#pragma unroll
    for (int r = 0; r < 4; ++r) inv[r] = 1.0f / ls[m][r];
#pragma unroll
    for (int d = 0; d < 4; ++d)
#pragma unroll
      for (int r = 0; r < 4; ++r)
        y[(rowQ0 + (m << 4) + (g << 2) + r) * 1024 + hc + (d << 4) + t] = (f16)(o[m][d][r] * inv[r]);
  }
}

// ---------------- launch ----------------
extern "C" void kernel_launch(void* const* d_in, const int* in_sizes, int n_in,
                              void* d_out, int out_size, void* d_ws, size_t ws_size,
                              hipStream_t stream) {
  const float* q = (const float*)d_in[0];
  const float* k = (const float*)d_in[1];
  const float* v = (const float*)d_in[2];
  const unsigned char* kpm = (const unsigned char*)d_in[3];
  const unsigned char* amask = (const unsigned char*)d_in[4];
  const float* Wq = (const float*)d_in[5];
  const float* bq = (const float*)d_in[6];
  const float* Wk = (const float*)d_in[7];
  const float* bk = (const float*)d_in[8];
  const float* Wv = (const float*)d_in[9];
  const float* bv = (const float*)d_in[10];
  const float* Wo = (const float*)d_in[11];
  const float* bo = (const float*)d_in[12];
  float* out = (float*)d_out;

  char* ws = (char*)d_ws;
  const size_t SZ = 16777216;  // bytes of one [8192,1024] f16 buffer
  f16* qb = (f16*)(ws + 0 * SZ);
  f16* kb = (f16*)(ws + 1 * SZ);
  f16* vb = (f16*)(ws + 2 * SZ);
  f16* qhp = (f16*)(ws + 3 * SZ);
  f16* khp = (f16*)(ws + 4 * SZ);
  f16* vhp = (f16*)(ws + 5 * SZ);
  f16* yb = (f16*)(ws + 6 * SZ);
  f16* wqb = (f16*)(ws + 7 * SZ + 0 * 2097152);
  f16* wkb = (f16*)(ws + 7 * SZ + 1 * 2097152);
  f16* wvb = (f16*)(ws + 7 * SZ + 2 * 2097152);
  f16* wob = (f16*)(ws + 7 * SZ + 3 * 2097152);
  int* flags = (int*)(ws + 7 * SZ + 4 * 2097152);

  cvt_qkv_kernel<<<24576, 256, 0, stream>>>(q, k, v, qb, kb, vb, flags);
  cvt_w_kernel<<<4096, 256, 0, stream>>>(Wq, Wk, Wv, Wo, wqb, wkb, wvb, wob);
  mask_flags_kernel<<<1024, 256, 0, stream>>>(amask, kpm, flags);
  gemm_bt<f16><<<512, 256, 0, stream>>>(qb, wqb, bq, qhp, 8192, 1024, 1024);
  gemm_bt<f16><<<512, 256, 0, stream>>>(kb, wkb, bk, khp, 8192, 1024, 1024);
  gemm_bt<f16><<<512, 256, 0, stream>>>(vb, wvb, bv, vhp, 8192, 1024, 1024);
  attn_kernel<<<1024, 256, 0, stream>>>(qhp, khp, vhp, amask, kpm, flags, yb);
  gemm_bt<float><<<512, 256, 0, stream>>>(yb, wob, bo, out, 8192, 1024, 1024);
}